// Round 1
// baseline (1023.530 us; speedup 1.0000x reference)
//
#include <hip/hip_runtime.h>
#include <hip/hip_bf16.h>

// ---------- types ----------
typedef float  f32x4  __attribute__((ext_vector_type(4)));
typedef short  bf16x8 __attribute__((ext_vector_type(8)));

#define EPI_QKV    0
#define EPI_SCORES 1
#define EPI_ATTV   2
#define EPI_PROJ   3
#define EPI_FF1    4
#define EPI_FF2    5

struct GP {
  const __hip_bfloat16* A;   // [M][K], k-contig, ldA
  const __hip_bfloat16* B;   // [N][K], k-contig, ldB  (pre-transposed weights)
  int M, N, K;
  int ldA, ldB;
  long long batchA, batchB;  // element strides per blockIdx.z
  const float *bias, *bias2, *bias3, *resid;
  float *outF;
  __hip_bfloat16 *outB0, *outB2, *outB3;
  float scale;
};

template<int EPI>
__device__ __forceinline__ void epi_store(const GP& p, int z, int gr, int gc, float v) {
  if (gr >= p.M || gc >= p.N) return;
  if constexpr (EPI == EPI_QKV) {
    int b = gr >> 9, t = gr & 511;
    int which = gc >> 9, hc = gc & 511, h = hc >> 6, c = hc & 63;
    size_t qi = (((size_t)(b * 8 + h) * 512 + t) << 6) + c;
    if (which == 0) {
      float val = v + p.bias[hc];
      p.outF[qi]  = val;                       // q fp32 (for rel dot)
      p.outB0[qi] = __float2bfloat16(val);     // q bf16 (for scores MFMA)
    } else if (which == 1) {
      float val = v + p.bias2[hc];
      p.outB2[qi] = __float2bfloat16(val);     // k bf16
    } else {
      float val = v + p.bias3[hc];             // v^T bf16: [b,h][c][t]
      p.outB3[(((size_t)(b * 8 + h) * 64 + c) << 9) + t] = __float2bfloat16(val);
    }
  } else if constexpr (EPI == EPI_SCORES) {
    p.outF[(size_t)z * 262144 + (size_t)gr * 512 + gc] = v * p.scale;
  } else if constexpr (EPI == EPI_ATTV) {
    int b = z >> 3, h = z & 7;                 // out -> concat [b*512+t][h*64+c]
    p.outB0[((size_t)(b * 512 + gr)) * 512 + h * 64 + gc] = __float2bfloat16(v);
  } else if constexpr (EPI == EPI_PROJ) {
    size_t o = (size_t)gr * 512 + gc;
    p.outF[o] = v + p.bias[gc] + p.resid[o];   // src_out = x + att_out
  } else if constexpr (EPI == EPI_FF1) {
    float x = v + p.bias[gc];
    float g = 0.5f * x * (1.0f + erff(x * 0.70710678118f));  // exact gelu
    p.outB0[(size_t)gr * 2048 + gc] = __float2bfloat16(g);
  } else {  // EPI_FF2
    size_t o = (size_t)gr * 512 + gc;
    p.outF[o] = v + p.bias[gc] + p.resid[o];   // out = y + ff_out
  }
}

// 128x128 tile, BK=64, 256 threads = 4 waves (2x2), 16x16x32 bf16 MFMA.
// LDS XOR-swizzle ((slot ^ (row&7))*16B) to keep ds_read_b128 ~conflict-free.
template<int EPI>
__global__ __launch_bounds__(256)
void gemm_k(GP p) {
  __shared__ __align__(16) __hip_bfloat16 As[128 * 64];
  __shared__ __align__(16) __hip_bfloat16 Bs[128 * 64];
  const int tid  = threadIdx.x;
  const int lane = tid & 63;
  const int wave = tid >> 6;
  const int wr = wave >> 1, wc = wave & 1;
  const int m0 = blockIdx.y * 128, n0 = blockIdx.x * 128;
  const int z  = blockIdx.z;
  const __hip_bfloat16* A = p.A + (size_t)z * p.batchA;
  const __hip_bfloat16* B = p.B + (size_t)z * p.batchB;

  f32x4 acc[4][4];
#pragma unroll
  for (int i = 0; i < 4; ++i)
#pragma unroll
    for (int j = 0; j < 4; ++j) acc[i][j] = (f32x4){0.f, 0.f, 0.f, 0.f};

  for (int kt = 0; kt < p.K; kt += 64) {
    __syncthreads();
#pragma unroll
    for (int i = 0; i < 4; ++i) {           // stage 16KB A + 16KB B (reg-staged)
      int o = i * 256 + tid;                // 16B units
      int row = o >> 3, s = o & 7;
      int ga = m0 + row; if (ga >= p.M) ga = p.M - 1;
      bf16x8 va = *(const bf16x8*)((const char*)A + ((size_t)ga * p.ldA + kt) * 2 + s * 16);
      *(bf16x8*)((char*)As + row * 128 + ((s ^ (row & 7)) * 16)) = va;
      int gb = n0 + row; if (gb >= p.N) gb = p.N - 1;
      bf16x8 vb = *(const bf16x8*)((const char*)B + ((size_t)gb * p.ldB + kt) * 2 + s * 16);
      *(bf16x8*)((char*)Bs + row * 128 + ((s ^ (row & 7)) * 16)) = vb;
    }
    __syncthreads();
#pragma unroll
    for (int kk = 0; kk < 2; ++kk) {
      int sl = kk * 4 + (lane >> 4);        // 16B slot of this lane's 8 k-elems
      bf16x8 af[4], bf_[4];
#pragma unroll
      for (int i = 0; i < 4; ++i) {
        int row = wr * 64 + i * 16 + (lane & 15);
        af[i] = *(const bf16x8*)((const char*)As + row * 128 + ((sl ^ (row & 7)) * 16));
      }
#pragma unroll
      for (int j = 0; j < 4; ++j) {
        int row = wc * 64 + j * 16 + (lane & 15);
        bf_[j] = *(const bf16x8*)((const char*)Bs + row * 128 + ((sl ^ (row & 7)) * 16));
      }
#pragma unroll
      for (int i = 0; i < 4; ++i)
#pragma unroll
        for (int j = 0; j < 4; ++j)
          acc[i][j] = __builtin_amdgcn_mfma_f32_16x16x32_bf16(af[i], bf_[j], acc[i][j], 0, 0, 0);
    }
  }
#pragma unroll
  for (int i = 0; i < 4; ++i)
#pragma unroll
    for (int j = 0; j < 4; ++j)
#pragma unroll
      for (int r = 0; r < 4; ++r) {
        int gr = m0 + wr * 64 + i * 16 + ((lane >> 4) << 2) + r;  // row=(lane>>4)*4+reg
        int gc = n0 + wc * 64 + j * 16 + (lane & 15);             // col=lane&15
        epi_store<EPI>(p, z, gr, gc, acc[i][j][r]);
      }
}

// rmsnorm: one block per row of 512; writes fp32 + bf16
__global__ __launch_bounds__(256)
void rmsnorm_k(const float* __restrict__ in, const float* __restrict__ w,
               float* __restrict__ outF, __hip_bfloat16* __restrict__ outB) {
  const int row = blockIdx.x;
  const float* x = in + (size_t)row * 512;
  const int tid = threadIdx.x;
  float a = x[tid], b = x[tid + 256];
  float ss = a * a + b * b;
#pragma unroll
  for (int off = 32; off > 0; off >>= 1) ss += __shfl_down(ss, off);
  __shared__ float red[4];
  if ((tid & 63) == 0) red[tid >> 6] = ss;
  __syncthreads();
  float tot = red[0] + red[1] + red[2] + red[3];
  float sc = rsqrtf(tot * (1.0f / 512.0f) + 1e-6f);
  float y0 = a * sc * w[tid], y1 = b * sc * w[tid + 256];
  size_t o = (size_t)row * 512;
  outF[o + tid] = y0;           outF[o + tid + 256] = y1;
  outB[o + tid] = __float2bfloat16(y0);
  outB[o + tid + 256] = __float2bfloat16(y1);
}

// Fused rel-bias + softmax. One block per (t,h), serving all 8 batches:
// rel_pos[h,t] (128KB) is read exactly once per launch. fp32 VALU dot (4 flop/B).
__global__ __launch_bounds__(256)
void rel_softmax_k(const float* __restrict__ qf, const float* __restrict__ rel_pos,
                   const float* __restrict__ scores, __hip_bfloat16* __restrict__ att) {
  const int t = blockIdx.x, h = blockIdx.y;
  __shared__ float qs[512];        // q[b=0..7][c=0..63] fp32
  __shared__ float logits[4096];   // [b][v]
  const int tid = threadIdx.x;
  for (int i = tid; i < 512; i += 256) {
    int b = i >> 6, c = i & 63;
    qs[i] = qf[(((size_t)(b * 8 + h) * 512 + t) << 6) + c];
  }
  for (int i = tid; i < 4096; i += 256) {
    int b = i >> 9, v = i & 511;
    logits[i] = scores[((size_t)(b * 8 + h) * 512 + t) * 512 + v];  // pre-scaled by 8
  }
  __syncthreads();
  const int j = tid & 15, g = tid >> 4;    // 16 lanes per v-row, 16 groups
  float4 q4[8];
#pragma unroll
  for (int b = 0; b < 8; ++b) q4[b] = *(const float4*)&qs[b * 64 + j * 4];
  const float* rb = rel_pos + ((size_t)h * 512 + t) * 512 * 64;
  for (int it = 0; it < 32; ++it) {
    int v = it * 16 + g;
    float4 r4 = *(const float4*)&rb[(size_t)v * 64 + j * 4];   // wave: 1KB coalesced
    float part[8];
#pragma unroll
    for (int b = 0; b < 8; ++b)
      part[b] = r4.x * q4[b].x + r4.y * q4[b].y + r4.z * q4[b].z + r4.w * q4[b].w;
#pragma unroll
    for (int off = 1; off < 16; off <<= 1)
#pragma unroll
      for (int b = 0; b < 8; ++b) part[b] += __shfl_xor(part[b], off);
    if (j < 8) logits[j * 512 + v] += part[j];
  }
  __syncthreads();
  const int wave = tid >> 6, lane = tid & 63;
  for (int b = wave; b < 8; b += 4) {       // each wave: 2 softmax rows
    float vals[8]; float mx = -3.0e38f;
#pragma unroll
    for (int i2 = 0; i2 < 8; ++i2) { vals[i2] = logits[b * 512 + i2 * 64 + lane]; mx = fmaxf(mx, vals[i2]); }
#pragma unroll
    for (int off = 32; off > 0; off >>= 1) mx = fmaxf(mx, __shfl_xor(mx, off));
    float s = 0.f;
#pragma unroll
    for (int i2 = 0; i2 < 8; ++i2) { vals[i2] = __expf(vals[i2] - mx); s += vals[i2]; }
#pragma unroll
    for (int off = 32; off > 0; off >>= 1) s += __shfl_xor(s, off);
    float inv = 1.0f / s;
    __hip_bfloat16* o = att + ((size_t)(b * 8 + h) * 512 + t) * 512;
#pragma unroll
    for (int i2 = 0; i2 < 8; ++i2) o[i2 * 64 + lane] = __float2bfloat16(vals[i2] * inv);
  }
}

// Wq/Wk/Wv [H][512][64] -> combined B-operand [1536 cols][512 d] bf16
__global__ __launch_bounds__(256)
void pack_qkv_w(const float* __restrict__ Wq, const float* __restrict__ Wk,
                const float* __restrict__ Wv, __hip_bfloat16* __restrict__ out) {
  int idx = blockIdx.x * 256 + threadIdx.x;
  if (idx >= 1536 * 512) return;
  int ncol = idx >> 9, d = idx & 511;
  int s = ncol >> 9, hc = ncol & 511, h = hc >> 6, c = hc & 63;
  const float* W = (s == 0) ? Wq : (s == 1) ? Wk : Wv;
  out[idx] = __float2bfloat16(W[((size_t)(h * 512 + d) << 6) + c]);
}

// out[n*Kd + k] = in[k*Nd + n], Kd = 1<<kshift
__global__ __launch_bounds__(256)
void transpose_bf16_k(const float* __restrict__ in, __hip_bfloat16* __restrict__ out,
                      int kshift, int Nd, int total) {
  int idx = blockIdx.x * 256 + threadIdx.x;
  if (idx >= total) return;
  int n = idx >> kshift, k = idx & ((1 << kshift) - 1);
  out[idx] = __float2bfloat16(in[(size_t)k * Nd + n]);
}

// ---------- workspace layout (bytes, all 256-aligned) ----------
enum : size_t {
  OFF_XF   = 0,                       // x fp32          8388608
  OFF_XB   = 8388608,                 // x bf16          4194304
  OFF_QF   = OFF_XB + 4194304,        // q fp32          8388608
  OFF_QB   = OFF_QF + 8388608,        // q bf16          4194304
  OFF_KB   = OFF_QB + 4194304,        // k bf16          4194304
  OFF_VT   = OFF_KB + 4194304,        // v^T bf16        4194304
  OFF_WQKV = OFF_VT + 4194304,        // W qkv bf16      1572864
  OFF_PWT  = OFF_WQKV + 1572864,      // proj_w^T bf16    524288
  OFF_F1T  = OFF_PWT + 524288,        // ff_w1^T bf16    2097152
  OFF_F2T  = OFF_F1T + 2097152,       // ff_w2^T bf16    2097152
  OFF_SC   = OFF_F2T + 2097152,       // scores fp32    67108864
  OFF_ATT  = OFF_SC + 67108864,       // att bf16       33554432
  OFF_CAT  = OFF_ATT + 33554432,      // concat bf16     4194304
  OFF_SO   = OFF_CAT + 4194304,       // src_out fp32    8388608
  OFF_YF   = OFF_SO + 8388608,        // y fp32          8388608
  OFF_YB   = OFF_YF + 8388608,        // y bf16          4194304
  OFF_H    = OFF_YB + 4194304,        // h bf16         16777216
  WS_NEED  = OFF_H + 16777216         // ~182 MB
};

extern "C" void kernel_launch(void* const* d_in, const int* in_sizes, int n_in,
                              void* d_out, int out_size, void* d_ws, size_t ws_size,
                              hipStream_t stream) {
  const float* src   = (const float*)d_in[0];
  const float* normw = (const float*)d_in[1];
  const float* Wq    = (const float*)d_in[2];
  const float* bq    = (const float*)d_in[3];
  const float* Wk    = (const float*)d_in[4];
  const float* bk    = (const float*)d_in[5];
  const float* Wv    = (const float*)d_in[6];
  const float* bv    = (const float*)d_in[7];
  const float* relp  = (const float*)d_in[8];
  const float* pw    = (const float*)d_in[9];
  const float* pb    = (const float*)d_in[10];
  const float* f1w   = (const float*)d_in[11];
  const float* f1b   = (const float*)d_in[12];
  const float* f2w   = (const float*)d_in[13];
  const float* f2b   = (const float*)d_in[14];
  float* out = (float*)d_out;
  char* ws = (char*)d_ws;

  float*          xf    = (float*)(ws + OFF_XF);
  __hip_bfloat16* xb    = (__hip_bfloat16*)(ws + OFF_XB);
  float*          qf    = (float*)(ws + OFF_QF);
  __hip_bfloat16* qb    = (__hip_bfloat16*)(ws + OFF_QB);
  __hip_bfloat16* kb    = (__hip_bfloat16*)(ws + OFF_KB);
  __hip_bfloat16* vT    = (__hip_bfloat16*)(ws + OFF_VT);
  __hip_bfloat16* wqkvb = (__hip_bfloat16*)(ws + OFF_WQKV);
  __hip_bfloat16* pwt   = (__hip_bfloat16*)(ws + OFF_PWT);
  __hip_bfloat16* f1t   = (__hip_bfloat16*)(ws + OFF_F1T);
  __hip_bfloat16* f2t   = (__hip_bfloat16*)(ws + OFF_F2T);
  float*          sc    = (float*)(ws + OFF_SC);
  __hip_bfloat16* attb  = (__hip_bfloat16*)(ws + OFF_ATT);
  __hip_bfloat16* catb  = (__hip_bfloat16*)(ws + OFF_CAT);
  float*          so    = (float*)(ws + OFF_SO);
  float*          yf    = (float*)(ws + OFF_YF);
  __hip_bfloat16* yb    = (__hip_bfloat16*)(ws + OFF_YB);
  __hip_bfloat16* hb    = (__hip_bfloat16*)(ws + OFF_H);

  // weight conversions (bf16, B-operand [N][K] layouts)
  pack_qkv_w<<<3072, 256, 0, stream>>>(Wq, Wk, Wv, wqkvb);
  transpose_bf16_k<<<1024, 256, 0, stream>>>(pw,  pwt, 9, 512,  262144);
  transpose_bf16_k<<<4096, 256, 0, stream>>>(f1w, f1t, 9, 2048, 1048576);
  transpose_bf16_k<<<4096, 256, 0, stream>>>(f2w, f2t, 11, 512, 1048576);

  // x = rmsnorm(src)
  rmsnorm_k<<<4096, 256, 0, stream>>>(src, normw, xf, xb);

  // QKV projection: [4096,512] @ [512,1536]
  {
    GP p{}; p.A = xb; p.B = wqkvb; p.M = 4096; p.N = 1536; p.K = 512;
    p.ldA = 512; p.ldB = 512; p.batchA = 0; p.batchB = 0;
    p.bias = bq; p.bias2 = bk; p.bias3 = bv;
    p.outF = qf; p.outB0 = qb; p.outB2 = kb; p.outB3 = vT;
    gemm_k<EPI_QKV><<<dim3(12, 32, 1), 256, 0, stream>>>(p);
  }
  // scores = (q @ k^T) * sqrt(64), per (b,h)
  {
    GP p{}; p.A = qb; p.B = kb; p.M = 512; p.N = 512; p.K = 64;
    p.ldA = 64; p.ldB = 64; p.batchA = 32768; p.batchB = 32768;
    p.outF = sc; p.scale = 8.0f;
    gemm_k<EPI_SCORES><<<dim3(4, 4, 64), 256, 0, stream>>>(p);
  }
  // att = softmax(scores + q . rel_pos)
  rel_softmax_k<<<dim3(512, 8), 256, 0, stream>>>(qf, relp, sc, attb);

  // out = att @ v  -> concat layout
  {
    GP p{}; p.A = attb; p.B = vT; p.M = 512; p.N = 64; p.K = 512;
    p.ldA = 512; p.ldB = 512; p.batchA = 262144; p.batchB = 32768;
    p.outB0 = catb;
    gemm_k<EPI_ATTV><<<dim3(1, 4, 64), 256, 0, stream>>>(p);
  }
  // src_out = x + (concat @ proj_w + proj_b)
  {
    GP p{}; p.A = catb; p.B = pwt; p.M = 4096; p.N = 512; p.K = 512;
    p.ldA = 512; p.ldB = 512; p.bias = pb; p.resid = xf; p.outF = so;
    gemm_k<EPI_PROJ><<<dim3(4, 32, 1), 256, 0, stream>>>(p);
  }
  // y = rmsnorm(src_out)
  rmsnorm_k<<<4096, 256, 0, stream>>>(so, normw, yf, yb);

  // h = gelu(y @ ff_w1 + b1)
  {
    GP p{}; p.A = yb; p.B = f1t; p.M = 4096; p.N = 2048; p.K = 512;
    p.ldA = 512; p.ldB = 512; p.bias = f1b; p.outB0 = hb;
    gemm_k<EPI_FF1><<<dim3(16, 32, 1), 256, 0, stream>>>(p);
  }
  // out = y + (h @ ff_w2 + b2)
  {
    GP p{}; p.A = hb; p.B = f2t; p.M = 4096; p.N = 512; p.K = 2048;
    p.ldA = 2048; p.ldB = 2048; p.bias = f2b; p.resid = yf; p.outF = out;
    gemm_k<EPI_FF2><<<dim3(4, 32, 1), 256, 0, stream>>>(p);
  }
}

// Round 3
// 874.592 us; speedup vs baseline: 1.1703x; 1.1703x over previous
//
#include <hip/hip_runtime.h>
#include <hip/hip_bf16.h>

// ---------- types ----------
typedef float  f32x4  __attribute__((ext_vector_type(4)));
typedef short  bf16x8 __attribute__((ext_vector_type(8)));

__device__ __forceinline__ short f2bf(float x) {
  __hip_bfloat16 h = __float2bfloat16(x);
  return *reinterpret_cast<short*>(&h);
}
__device__ __forceinline__ bf16x8 cvt8(float4 a, float4 b) {
  bf16x8 r;
  r[0] = f2bf(a.x); r[1] = f2bf(a.y); r[2] = f2bf(a.z); r[3] = f2bf(a.w);
  r[4] = f2bf(b.x); r[5] = f2bf(b.y); r[6] = f2bf(b.z); r[7] = f2bf(b.w);
  return r;
}

#define EPI_QKV    0
#define EPI_SCORES 1
#define EPI_ATTV   2
#define EPI_PROJ   3
#define EPI_FF1    4
#define EPI_FF2    5

struct GP {
  const __hip_bfloat16* A;   // [M][K], k-contig, ldA
  const __hip_bfloat16* B;   // [N][K], k-contig, ldB  (pre-transposed weights)
  int M, N, K;
  int ldA, ldB;
  long long batchA, batchB;  // element strides per blockIdx.z
  const float *bias, *bias2, *bias3, *resid;
  float *outF;
  __hip_bfloat16 *outB0, *outB2, *outB3;
  float scale;
};

template<int EPI>
__device__ __forceinline__ void epi_store(const GP& p, int z, int gr, int gc, float v) {
  if constexpr (EPI == EPI_QKV) {
    int b = gr >> 9, t = gr & 511;
    int which = gc >> 9, hc = gc & 511, h = hc >> 6, c = hc & 63;
    size_t qi = (((size_t)(b * 8 + h) * 512 + t) << 6) + c;
    if (which == 0)      p.outB0[qi] = __float2bfloat16(v + p.bias[hc]);   // q bf16
    else if (which == 1) p.outB2[qi] = __float2bfloat16(v + p.bias2[hc]);  // k bf16
    else p.outB3[(((size_t)(b * 8 + h) * 64 + c) << 9) + t] =              // v^T bf16
           __float2bfloat16(v + p.bias3[hc]);
  } else if constexpr (EPI == EPI_SCORES) {
    p.outF[(size_t)z * 262144 + (size_t)gr * 512 + gc] = v * p.scale;
  } else if constexpr (EPI == EPI_ATTV) {
    int b = z >> 3, h = z & 7;                 // out -> concat [b*512+t][h*64+c]
    p.outB0[((size_t)(b * 512 + gr)) * 512 + h * 64 + gc] = __float2bfloat16(v);
  } else if constexpr (EPI == EPI_PROJ) {
    size_t o = (size_t)gr * 512 + gc;
    p.outF[o] = v + p.bias[gc] + p.resid[o];   // src_out = x + att_out
  } else if constexpr (EPI == EPI_FF1) {
    float x = v + p.bias[gc];
    float g = 0.5f * x * (1.0f + erff(x * 0.70710678118f));  // exact gelu
    p.outB0[(size_t)gr * 2048 + gc] = __float2bfloat16(g);
  } else {  // EPI_FF2
    size_t o = (size_t)gr * 512 + gc;
    p.outF[o] = v + p.bias[gc] + p.resid[o];   // out = y + ff_out
  }
}

// BMxBN tile, BK=64, 256 threads = 4 waves (2x2), 16x16x32 bf16 MFMA.
// LDS XOR-swizzle ((slot ^ (row&7))*16B) keeps ds_read_b128 ~conflict-free.
// All problem dims divide the tile exactly (no bounds checks needed).
template<int EPI, int BM, int BN>
__global__ __launch_bounds__(256)
void gemm_k(GP p) {
  constexpr int MI = BM / 32, NI = BN / 32;
  __shared__ __align__(16) __hip_bfloat16 As[BM * 64];
  __shared__ __align__(16) __hip_bfloat16 Bs[BN * 64];
  const int tid  = threadIdx.x;
  const int lane = tid & 63;
  const int wave = tid >> 6;
  const int wr = wave >> 1, wc = wave & 1;
  const int m0 = blockIdx.y * BM, n0 = blockIdx.x * BN;
  const int z  = blockIdx.z;
  const __hip_bfloat16* A = p.A + (size_t)z * p.batchA;
  const __hip_bfloat16* B = p.B + (size_t)z * p.batchB;

  f32x4 acc[MI][NI];
#pragma unroll
  for (int i = 0; i < MI; ++i)
#pragma unroll
    for (int j = 0; j < NI; ++j) acc[i][j] = (f32x4){0.f, 0.f, 0.f, 0.f};

  for (int kt = 0; kt < p.K; kt += 64) {
    __syncthreads();
#pragma unroll
    for (int i = 0; i < BM / 32; ++i) {     // stage A: 32 rows per pass
      int o = i * 256 + tid, row = o >> 3, s = o & 7;
      bf16x8 va = *(const bf16x8*)((const char*)A + ((size_t)(m0 + row) * p.ldA + kt) * 2 + s * 16);
      *(bf16x8*)((char*)As + row * 128 + ((s ^ (row & 7)) * 16)) = va;
    }
#pragma unroll
    for (int i = 0; i < BN / 32; ++i) {     // stage B
      int o = i * 256 + tid, row = o >> 3, s = o & 7;
      bf16x8 vb = *(const bf16x8*)((const char*)B + ((size_t)(n0 + row) * p.ldB + kt) * 2 + s * 16);
      *(bf16x8*)((char*)Bs + row * 128 + ((s ^ (row & 7)) * 16)) = vb;
    }
    __syncthreads();
#pragma unroll
    for (int kk = 0; kk < 2; ++kk) {
      int sl = kk * 4 + (lane >> 4);
      bf16x8 af[MI], bfr[NI];
#pragma unroll
      for (int i = 0; i < MI; ++i) {
        int row = wr * (BM / 2) + i * 16 + (lane & 15);
        af[i] = *(const bf16x8*)((const char*)As + row * 128 + ((sl ^ (row & 7)) * 16));
      }
#pragma unroll
      for (int j = 0; j < NI; ++j) {
        int row = wc * (BN / 2) + j * 16 + (lane & 15);
        bfr[j] = *(const bf16x8*)((const char*)Bs + row * 128 + ((sl ^ (row & 7)) * 16));
      }
#pragma unroll
      for (int i = 0; i < MI; ++i)
#pragma unroll
        for (int j = 0; j < NI; ++j)
          acc[i][j] = __builtin_amdgcn_mfma_f32_16x16x32_bf16(af[i], bfr[j], acc[i][j], 0, 0, 0);
    }
  }
#pragma unroll
  for (int i = 0; i < MI; ++i)
#pragma unroll
    for (int j = 0; j < NI; ++j)
#pragma unroll
      for (int r = 0; r < 4; ++r) {
        int gr = m0 + wr * (BM / 2) + i * 16 + ((lane >> 4) << 2) + r;
        int gc = n0 + wc * (BN / 2) + j * 16 + (lane & 15);
        epi_store<EPI>(p, z, gr, gc, acc[i][j][r]);
      }
}

// rmsnorm: one block per row of 512; writes fp32 + bf16
__global__ __launch_bounds__(256)
void rmsnorm_k(const float* __restrict__ in, const float* __restrict__ w,
               float* __restrict__ outF, __hip_bfloat16* __restrict__ outB) {
  const int row = blockIdx.x;
  const float* x = in + (size_t)row * 512;
  const int tid = threadIdx.x;
  float a = x[tid], b = x[tid + 256];
  float ss = a * a + b * b;
#pragma unroll
  for (int off = 32; off > 0; off >>= 1) ss += __shfl_down(ss, off);
  __shared__ float red[4];
  if ((tid & 63) == 0) red[tid >> 6] = ss;
  __syncthreads();
  float tot = red[0] + red[1] + red[2] + red[3];
  float sc = rsqrtf(tot * (1.0f / 512.0f) + 1e-6f);
  float y0 = a * sc * w[tid], y1 = b * sc * w[tid + 256];
  size_t o = (size_t)row * 512;
  outF[o + tid] = y0;           outF[o + tid + 256] = y1;
  outB[o + tid] = __float2bfloat16(y0);
  outB[o + tid + 256] = __float2bfloat16(y1);
}

// Fused rel-bias + softmax, MFMA version. One block per (t,h) serving all 8
// batches: rel_pos[h,t] (128KB) streams from HBM exactly once. For fixed
// (h,t): rel_out[v,b] = sum_c rel[v,c]*q[b,c] -> MFMA M=512(v) N=8(b) K=64.
// A-frags load fp32 straight from global (cvt to bf16 in regs, no staging);
// acc initializes from scores (fused read); D -> LDS logits -> softmax.
__global__ __launch_bounds__(256)
void rel_softmax_k(const __hip_bfloat16* __restrict__ qb, const float* __restrict__ rel_pos,
                   const float* __restrict__ scores, __hip_bfloat16* __restrict__ att) {
  const int t = blockIdx.x, h = blockIdx.y;
  __shared__ float logits[8 * 520];          // [b][v], stride 520 (bank-spread)
  const int tid = threadIdx.x, lane = tid & 63, wave = tid >> 6;
  const int bb = lane & 15, hi = lane >> 4;

  // B-fragment: q[b][k], col=lane&15 -> b, k-chunk=(lane>>4)*8
  bf16x8 qfrag0, qfrag1;
  if (bb < 8) {
    const __hip_bfloat16* qptr = qb + (((size_t)(bb * 8 + h) * 512 + t) << 6);
    qfrag0 = *(const bf16x8*)(qptr + hi * 8);
    qfrag1 = *(const bf16x8*)(qptr + 32 + hi * 8);
  } else {
    qfrag0 = (bf16x8){0,0,0,0,0,0,0,0};
    qfrag1 = (bf16x8){0,0,0,0,0,0,0,0};
  }
  const float* rb = rel_pos + ((size_t)h * 512 + t) * 512 * 64;
  const float* sb = scores + (((size_t)((bb & 7) * 8 + h) * 512 + t) << 9);

#pragma unroll
  for (int mi = 0; mi < 8; ++mi) {           // wave handles m-tiles wave*8..+7
    int m = wave * 8 + mi;
    int vb = m * 16 + hi * 4;                // this lane's D-row base (v)
    f32x4 acc = (f32x4){0.f, 0.f, 0.f, 0.f};
    if (bb < 8) acc = *(const f32x4*)(sb + vb);   // scores pre-scaled by 8
    int vr = m * 16 + bb;                    // A-frag row this lane loads
    const float* ar = rb + (size_t)vr * 64 + hi * 8;
    float4 a0 = *(const float4*)ar,        a1 = *(const float4*)(ar + 4);
    float4 a2 = *(const float4*)(ar + 32), a3 = *(const float4*)(ar + 36);
    bf16x8 af0 = cvt8(a0, a1), af1 = cvt8(a2, a3);
    acc = __builtin_amdgcn_mfma_f32_16x16x32_bf16(af0, qfrag0, acc, 0, 0, 0);
    acc = __builtin_amdgcn_mfma_f32_16x16x32_bf16(af1, qfrag1, acc, 0, 0, 0);
    if (bb < 8) *(f32x4*)&logits[bb * 520 + vb] = acc;
  }
  __syncthreads();

  for (int b = wave; b < 8; b += 4) {        // each wave: 2 softmax rows
    float vals[8]; float mx = -3.0e38f;
#pragma unroll
    for (int i2 = 0; i2 < 8; ++i2) { vals[i2] = logits[b * 520 + i2 * 64 + lane]; mx = fmaxf(mx, vals[i2]); }
#pragma unroll
    for (int off = 32; off > 0; off >>= 1) mx = fmaxf(mx, __shfl_xor(mx, off));
    float s = 0.f;
#pragma unroll
    for (int i2 = 0; i2 < 8; ++i2) { vals[i2] = __expf(vals[i2] - mx); s += vals[i2]; }
#pragma unroll
    for (int off = 32; off > 0; off >>= 1) s += __shfl_xor(s, off);
    float inv = 1.0f / s;
    __hip_bfloat16* o = att + ((size_t)(b * 8 + h) * 512 + t) * 512;
#pragma unroll
    for (int i2 = 0; i2 < 8; ++i2) o[i2 * 64 + lane] = __float2bfloat16(vals[i2] * inv);
  }
}

// Coalesced LDS-tiled transpose: in [K][N] fp32 -> out [N][K] bf16.
// grid (N/32, K/32), 256 threads (32x8, 4 row-iters).
__global__ __launch_bounds__(256)
void transpose_bf16_k(const float* __restrict__ in, __hip_bfloat16* __restrict__ out,
                      int K, int N) {
  __shared__ float tile[32][33];
  const int tx = threadIdx.x & 31, ty = threadIdx.x >> 5;
  const int n0 = blockIdx.x * 32, k0 = blockIdx.y * 32;
#pragma unroll
  for (int i = 0; i < 4; ++i)
    tile[ty + i * 8][tx] = in[(size_t)(k0 + ty + i * 8) * N + n0 + tx];
  __syncthreads();
#pragma unroll
  for (int i = 0; i < 4; ++i)
    out[(size_t)(n0 + ty + i * 8) * K + k0 + tx] = __float2bfloat16(tile[tx][ty + i * 8]);
}

// Wq/Wk/Wv [H][512][64] -> combined B-operand [1536 cols][512 d] bf16, coalesced.
// grid (2, 16, 24): (c-tile, d-tile, s*8+h)
__global__ __launch_bounds__(256)
void pack_qkv_w(const float* __restrict__ Wq, const float* __restrict__ Wk,
                const float* __restrict__ Wv, __hip_bfloat16* __restrict__ out) {
  __shared__ float tile[32][33];
  const int s = blockIdx.z >> 3, h = blockIdx.z & 7;
  const float* W = ((s == 0) ? Wq : (s == 1) ? Wk : Wv) + (size_t)h * 512 * 64;
  const int tx = threadIdx.x & 31, ty = threadIdx.x >> 5;
  const int c0 = blockIdx.x * 32, d0 = blockIdx.y * 32;
#pragma unroll
  for (int i = 0; i < 4; ++i)
    tile[ty + i * 8][tx] = W[(size_t)(d0 + ty + i * 8) * 64 + c0 + tx];
  __syncthreads();
#pragma unroll
  for (int i = 0; i < 4; ++i)
    out[(size_t)s * 262144 + (size_t)(h * 64 + c0 + ty + i * 8) * 512 + d0 + tx] =
        __float2bfloat16(tile[tx][ty + i * 8]);
}

// ---------- workspace layout (bytes) ----------
enum : size_t {
  OFF_XF   = 0,                       // x fp32          8388608
  OFF_XB   = 8388608,                 // x bf16          4194304
  OFF_QB   = OFF_XB + 4194304,        // q bf16          4194304
  OFF_KB   = OFF_QB + 4194304,        // k bf16          4194304
  OFF_VT   = OFF_KB + 4194304,        // v^T bf16        4194304
  OFF_WQKV = OFF_VT + 4194304,        // W qkv bf16      1572864
  OFF_PWT  = OFF_WQKV + 1572864,      // proj_w^T bf16    524288
  OFF_F1T  = OFF_PWT + 524288,        // ff_w1^T bf16    2097152
  OFF_F2T  = OFF_F1T + 2097152,       // ff_w2^T bf16    2097152
  OFF_SC   = OFF_F2T + 2097152,       // scores fp32    67108864
  OFF_ATT  = OFF_SC + 67108864,       // att bf16       33554432
  OFF_CAT  = OFF_ATT + 33554432,      // concat bf16     4194304
  OFF_SO   = OFF_CAT + 4194304,       // src_out fp32    8388608
  OFF_YF   = OFF_SO + 8388608,        // y fp32          8388608
  OFF_YB   = OFF_YF + 8388608,        // y bf16          4194304
  OFF_H    = OFF_YB + 4194304         // h bf16         16777216
};

extern "C" void kernel_launch(void* const* d_in, const int* in_sizes, int n_in,
                              void* d_out, int out_size, void* d_ws, size_t ws_size,
                              hipStream_t stream) {
  const float* src   = (const float*)d_in[0];
  const float* normw = (const float*)d_in[1];
  const float* Wq    = (const float*)d_in[2];
  const float* bq    = (const float*)d_in[3];
  const float* Wk    = (const float*)d_in[4];
  const float* bk    = (const float*)d_in[5];
  const float* Wv    = (const float*)d_in[6];
  const float* bv    = (const float*)d_in[7];
  const float* relp  = (const float*)d_in[8];
  const float* pw    = (const float*)d_in[9];
  const float* pb    = (const float*)d_in[10];
  const float* f1w   = (const float*)d_in[11];
  const float* f1b   = (const float*)d_in[12];
  const float* f2w   = (const float*)d_in[13];
  const float* f2b   = (const float*)d_in[14];
  float* out = (float*)d_out;
  char* ws = (char*)d_ws;

  float*          xf    = (float*)(ws + OFF_XF);
  __hip_bfloat16* xb    = (__hip_bfloat16*)(ws + OFF_XB);
  __hip_bfloat16* qb    = (__hip_bfloat16*)(ws + OFF_QB);
  __hip_bfloat16* kb    = (__hip_bfloat16*)(ws + OFF_KB);
  __hip_bfloat16* vT    = (__hip_bfloat16*)(ws + OFF_VT);
  __hip_bfloat16* wqkvb = (__hip_bfloat16*)(ws + OFF_WQKV);
  __hip_bfloat16* pwt   = (__hip_bfloat16*)(ws + OFF_PWT);
  __hip_bfloat16* f1t   = (__hip_bfloat16*)(ws + OFF_F1T);
  __hip_bfloat16* f2t   = (__hip_bfloat16*)(ws + OFF_F2T);
  float*          sc    = (float*)(ws + OFF_SC);
  __hip_bfloat16* attb  = (__hip_bfloat16*)(ws + OFF_ATT);
  __hip_bfloat16* catb  = (__hip_bfloat16*)(ws + OFF_CAT);
  float*          so    = (float*)(ws + OFF_SO);
  float*          yf    = (float*)(ws + OFF_YF);
  __hip_bfloat16* yb    = (__hip_bfloat16*)(ws + OFF_YB);
  __hip_bfloat16* hb    = (__hip_bfloat16*)(ws + OFF_H);

  // weight conversions (bf16, B-operand [N][K] layouts) — coalesced LDS-tiled
  pack_qkv_w<<<dim3(2, 16, 24), 256, 0, stream>>>(Wq, Wk, Wv, wqkvb);
  transpose_bf16_k<<<dim3(16, 16), 256, 0, stream>>>(pw,  pwt, 512, 512);
  transpose_bf16_k<<<dim3(64, 16), 256, 0, stream>>>(f1w, f1t, 512, 2048);
  transpose_bf16_k<<<dim3(16, 64), 256, 0, stream>>>(f2w, f2t, 2048, 512);

  // x = rmsnorm(src)
  rmsnorm_k<<<4096, 256, 0, stream>>>(src, normw, xf, xb);

  // QKV projection: [4096,512] @ [512,1536]   (768 blocks = 3/CU)
  {
    GP p{}; p.A = xb; p.B = wqkvb; p.M = 4096; p.N = 1536; p.K = 512;
    p.ldA = 512; p.ldB = 512;
    p.bias = bq; p.bias2 = bk; p.bias3 = bv;
    p.outB0 = qb; p.outB2 = kb; p.outB3 = vT;
    gemm_k<EPI_QKV, 64, 128><<<dim3(12, 64, 1), 256, 0, stream>>>(p);
  }
  // scores = (q @ k^T) * sqrt(64), per (b,h)   (1024 blocks)
  {
    GP p{}; p.A = qb; p.B = kb; p.M = 512; p.N = 512; p.K = 64;
    p.ldA = 64; p.ldB = 64; p.batchA = 32768; p.batchB = 32768;
    p.outF = sc; p.scale = 8.0f;
    gemm_k<EPI_SCORES, 128, 128><<<dim3(4, 4, 64), 256, 0, stream>>>(p);
  }
  // att = softmax(scores + q . rel_pos)   (MFMA rel, HBM-streaming)
  rel_softmax_k<<<dim3(512, 8), 256, 0, stream>>>(qb, relp, sc, attb);

  // out = att @ v -> concat layout   (512 blocks)
  {
    GP p{}; p.A = attb; p.B = vT; p.M = 512; p.N = 64; p.K = 512;
    p.ldA = 512; p.ldB = 512; p.batchA = 262144; p.batchB = 32768;
    p.outB0 = catb;
    gemm_k<EPI_ATTV, 64, 64><<<dim3(1, 8, 64), 256, 0, stream>>>(p);
  }
  // src_out = x + (concat @ proj_w + proj_b)   (512 blocks)
  {
    GP p{}; p.A = catb; p.B = pwt; p.M = 4096; p.N = 512; p.K = 512;
    p.ldA = 512; p.ldB = 512; p.bias = pb; p.resid = xf; p.outF = so;
    gemm_k<EPI_PROJ, 64, 64><<<dim3(8, 64, 1), 256, 0, stream>>>(p);
  }
  // y = rmsnorm(src_out)
  rmsnorm_k<<<4096, 256, 0, stream>>>(so, normw, yf, yb);

  // h = gelu(y @ ff_w1 + b1)   (512 blocks)
  {
    GP p{}; p.A = yb; p.B = f1t; p.M = 4096; p.N = 2048; p.K = 512;
    p.ldA = 512; p.ldB = 512; p.bias = f1b; p.outB0 = hb;
    gemm_k<EPI_FF1, 128, 128><<<dim3(16, 32, 1), 256, 0, stream>>>(p);
  }
  // out = y + (h @ ff_w2 + b2)   (512 blocks)
  {
    GP p{}; p.A = hb; p.B = f2t; p.M = 4096; p.N = 512; p.K = 2048;
    p.ldA = 2048; p.ldB = 2048; p.bias = f2b; p.resid = yf; p.outF = out;
    gemm_k<EPI_FF2, 64, 64><<<dim3(8, 64, 1), 256, 0, stream>>>(p);
  }
}